// Round 10
// baseline (518.676 us; speedup 1.0000x reference)
//
#include <hip/hip_runtime.h>

// Problem constants
constexpr int NB = 8;    // batch
constexpr int NC = 32;   // channels
constexpr int NV = 512;  // vertices
constexpr int NL = 256;  // features
constexpr float F_ALPHA = 0.05f;
constexpr float F_BETA  = 0.95f;   // == 1 - F_ALPHA (used for both roles)

typedef __bf16 bf16x8 __attribute__((ext_vector_type(8)));
typedef float  f32x4  __attribute__((ext_vector_type(4)));

// async global->LDS, 16B per lane; LDS dest = wave-uniform base + lane*16
__device__ __forceinline__ void async_ld16(const void* g, void* l) {
  __builtin_amdgcn_global_load_lds(
      (const __attribute__((address_space(1))) void*)g,
      (__attribute__((address_space(3))) void*)l, 16, 0, 0);
}

// ---------------- prep kernels ----------------

// partial column sums of adj: partial[n, chunk, w] = sum_{v in chunk*64..+64} adj[n,v,w]
__global__ void k_colsum_part(const float* __restrict__ adj, float* __restrict__ partial) {
  int idx = blockIdx.x * 256 + threadIdx.x;       // NB*8*NV = 32768
  int w = idx & 511;
  int chunk = (idx >> 9) & 7;
  int n = idx >> 12;
  const float* p = adj + n * (NV * NV) + chunk * 64 * NV + w;
  float s = 0.f;
#pragma unroll
  for (int v = 0; v < 64; ++v) s += p[v * NV];
  partial[idx] = s;
}

__global__ void k_dinv(const float* __restrict__ partial, float* __restrict__ dinv) {
  int idx = blockIdx.x * 256 + threadIdx.x;       // NB*NV = 4096
  int w = idx & 511;
  int n = idx >> 9;
  float s = 1.f;                                   // +1 from the identity on the diagonal
#pragma unroll
  for (int j = 0; j < 8; ++j) s += partial[n * 4096 + j * 512 + w];
  dinv[idx] = 1.f / s;
}

// a_bf16[n,v,w] = (adj[n,v,w] + (v==w)) * dinv[n,w]
__global__ void k_prep_a(const float* __restrict__ adj, const float* __restrict__ dinv,
                         __bf16* __restrict__ a) {
  int idx = blockIdx.x * 256 + threadIdx.x;       // NB*NV*NV
  int w = idx & 511;
  int v = (idx >> 9) & 511;
  int n = idx >> 18;
  float val = adj[idx] + (v == w ? 1.0f : 0.0f);
  a[idx] = (__bf16)(val * dinv[(n << 9) | w]);
}

// Wt[l,k] = W[k,l] in bf16
__global__ void k_prep_wt(const float* __restrict__ W, __bf16* __restrict__ Wt) {
  int idx = blockIdx.x * 256 + threadIdx.x;       // 65536
  int l = idx >> 8, k = idx & 255;
  Wt[idx] = (__bf16)W[(k << 8) | l];
}

// Folded conv weights, k-major: cwT[k][o], 96 x 32 fp32 (12 KiB).
//   k <  32 (x group):  Wx[o,k] + alpha*(W1[o,k] + W2[o,k])   [since h_g = alpha*x + beta*D_g]
//   32<=k<64 (D1 group): beta*W1[o,k-32]
//   64<=k<96 (D2 group): beta*W2[o,k-64]
__global__ void k_prep_cwt(const float* __restrict__ cw, float* __restrict__ cwT) {
  int idx = blockIdx.x * 256 + threadIdx.x;       // 3072
  if (idx < 3072) {
    int k = idx >> 5, o = idx & 31;
    float v;
    if (k < 32)      v = cw[o * 96 + k] + F_ALPHA * (cw[o * 96 + 32 + k] + cw[o * 96 + 64 + k]);
    else             v = F_BETA * cw[o * 96 + k];
    cwT[idx] = v;
  }
}

// ---------------- GEMM 1: hw^T = Wt @ B^T (+ epilogue) ----------------
// Per pair p=(n,c): acc[l][w] = sum_k Wt[l][k] * B[w][k], stored at hw[n,c,l,w].
// BF32: B-source is fp32 (x, layout [n,c,v,l]); else bf16 (D1, layout [n,v,c,l]).
// EPI 0: hw = acc + b[l]                       (first propagation: hw1 = xW + b)
// EPI 1: hw = alpha*hwprev + beta*(acc + b[l]) (second: hw2 = alpha*hw1 + beta*(D1*W + b),
//                                              exact since h1 = alpha*x + beta*D1, xW = hw1 - b)
template <bool BF32, int EPI>
__global__ __launch_bounds__(256, 2)
void k_gemm_wt(const __bf16* __restrict__ Wt, const void* __restrict__ Bsrc,
               const float* __restrict__ bias, __bf16* __restrict__ hw,
               const __bf16* __restrict__ hwprev) {
  __shared__ __align__(16) char lds[32768];
  char* ldsA = lds;
  char* ldsB = lds + 16384;

  const int tid = threadIdx.x;
  const int bid = blockIdx.x;
  const int p = bid >> 3;            // pair index n*NC+c
  const int mtile = (bid >> 2) & 1;  // M=256 -> 2 tiles of 128
  const int ntile = bid & 3;         // N=512 -> 4 tiles of 128
  const int n = p >> 5, c = p & 31;

  int Bbase, Bstride;
  if (BF32) { Bbase = p * (NV * NL); Bstride = NL; }               // x[n,c,w,k]
  else      { Bbase = n * (NV * NC * NL) + c * NL; Bstride = NC * NL; } // D1[n,w,c,k]

  const int wave = tid >> 6, lane = tid & 63;
  const int quad = lane >> 4, l16 = lane & 15;
  const int wm = wave >> 1, wn = wave & 1;
  const int wbase = (tid & ~63) * 16;

  f32x4 acc[4][4];
#pragma unroll
  for (int i = 0; i < 4; ++i)
#pragma unroll
    for (int j = 0; j < 4; ++j) acc[i][j] = (f32x4){0.f, 0.f, 0.f, 0.f};

  for (int kt = 0; kt < 256 / 64; ++kt) {
    __syncthreads();
    // stage A = Wt tile [128 x 64], swizzled
#pragma unroll
    for (int j = 0; j < 4; ++j) {
      int pos = j * 4096 + tid * 16;
      int row = pos >> 7;
      int kb = (pos & 127) ^ ((row & 7) * 16);
      const __bf16* g = Wt + (mtile * 128 + row) * 256 + kt * 64 + (kb >> 1);
      async_ld16(g, ldsA + j * 4096 + wbase);
    }
    // stage B tile [128 x 64]
    if (BF32) {
      const float* Bf = (const float*)Bsrc;
#pragma unroll
      for (int j = 0; j < 4; ++j) {
        int pos = j * 4096 + tid * 16;
        int row = pos >> 7;
        int kb = (pos & 127) ^ ((row & 7) * 16);
        const float* g = Bf + Bbase + (ntile * 128 + row) * Bstride + kt * 64 + (kb >> 1);
        float4 f0 = *(const float4*)g;
        float4 f1 = *(const float4*)(g + 4);
        bf16x8 vv;
        vv[0] = (__bf16)f0.x; vv[1] = (__bf16)f0.y; vv[2] = (__bf16)f0.z; vv[3] = (__bf16)f0.w;
        vv[4] = (__bf16)f1.x; vv[5] = (__bf16)f1.y; vv[6] = (__bf16)f1.z; vv[7] = (__bf16)f1.w;
        *(bf16x8*)(ldsB + pos) = vv;
      }
    } else {
      const __bf16* Bf = (const __bf16*)Bsrc;
#pragma unroll
      for (int j = 0; j < 4; ++j) {
        int pos = j * 4096 + tid * 16;
        int row = pos >> 7;
        int kb = (pos & 127) ^ ((row & 7) * 16);
        const __bf16* g = Bf + Bbase + (ntile * 128 + row) * Bstride + kt * 64 + (kb >> 1);
        async_ld16(g, ldsB + j * 4096 + wbase);
      }
    }
    __syncthreads();
#pragma unroll
    for (int ks = 0; ks < 2; ++ks) {
      bf16x8 af[4], bfr[4];
#pragma unroll
      for (int mb = 0; mb < 4; ++mb) {
        int m = wm * 64 + mb * 16 + l16;
        int kb = (ks * 64 + quad * 16) ^ ((m & 7) * 16);
        af[mb] = *(const bf16x8*)(ldsA + m * 128 + kb);
      }
#pragma unroll
      for (int nb = 0; nb < 4; ++nb) {
        int nn = wn * 64 + nb * 16 + l16;
        int kb = (ks * 64 + quad * 16) ^ ((nn & 7) * 16);
        bfr[nb] = *(const bf16x8*)(ldsB + nn * 128 + kb);
      }
#pragma unroll
      for (int mb = 0; mb < 4; ++mb)
#pragma unroll
        for (int nb = 0; nb < 4; ++nb)
          acc[mb][nb] = __builtin_amdgcn_mfma_f32_16x16x32_bf16(af[mb], bfr[nb], acc[mb][nb], 0, 0, 0);
    }
  }
  // epilogue: hw[n,c, l, w]
  const size_t obase = (size_t)p * (NL * NV) + mtile * 128 * NV + ntile * 128;
  __bf16* outp = hw + obase;
  const __bf16* prevp = (EPI == 1) ? hwprev + obase : nullptr;
#pragma unroll
  for (int mb = 0; mb < 4; ++mb) {
#pragma unroll
    for (int r = 0; r < 4; ++r) {
      int ml = wm * 64 + mb * 16 + quad * 4 + r;
      float bv = bias[mtile * 128 + ml];
#pragma unroll
      for (int nb = 0; nb < 4; ++nb) {
        int nl = wn * 64 + nb * 16 + l16;
        if (EPI == 0) {
          outp[ml * NV + nl] = (__bf16)(acc[mb][nb][r] + bv);
        } else {
          float pv = (float)prevp[ml * NV + nl];
          outp[ml * NV + nl] = (__bf16)(F_ALPHA * pv + F_BETA * (acc[mb][nb][r] + bv));
        }
      }
    }
  }
}

// ---------------- GEMM 2: D = a @ hw (raw diffusion term, no x epilogue) ----------------
// Per batch n: D[v, col=(c,l)] = sum_w a[n,v,w] * hw[n,c,l,w]; D[n,v,c,l] out (bf16).
__global__ __launch_bounds__(256, 2)
void k_gemm_a(const __bf16* __restrict__ abuf, const __bf16* __restrict__ hw,
              __bf16* __restrict__ dout) {
  __shared__ __align__(16) char lds[32768];
  char* ldsA = lds;
  char* ldsB = lds + 16384;

  const int tid = threadIdx.x;
  const int bid = blockIdx.x;
  const int n = bid >> 8;
  const int mtile = (bid >> 6) & 3;  // M=512 -> 4
  const int ntile = bid & 63;        // N=8192 -> 64

  const __bf16* Ab = abuf + n * (NV * NV) + mtile * 128 * NV;        // rows v, stride 512
  const __bf16* Bb = hw + n * (NC * NL * NV) + ntile * 128 * NV;     // rows col, stride 512

  const int wave = tid >> 6, lane = tid & 63;
  const int quad = lane >> 4, l16 = lane & 15;
  const int wm = wave >> 1, wn = wave & 1;
  const int wbase = (tid & ~63) * 16;

  f32x4 acc[4][4];
#pragma unroll
  for (int i = 0; i < 4; ++i)
#pragma unroll
    for (int j = 0; j < 4; ++j) acc[i][j] = (f32x4){0.f, 0.f, 0.f, 0.f};

  for (int kt = 0; kt < 512 / 64; ++kt) {
    __syncthreads();
#pragma unroll
    for (int j = 0; j < 4; ++j) {
      int pos = j * 4096 + tid * 16;
      int row = pos >> 7;
      int kb = (pos & 127) ^ ((row & 7) * 16);
      async_ld16(Ab + row * NV + kt * 64 + (kb >> 1), ldsA + j * 4096 + wbase);
    }
#pragma unroll
    for (int j = 0; j < 4; ++j) {
      int pos = j * 4096 + tid * 16;
      int row = pos >> 7;
      int kb = (pos & 127) ^ ((row & 7) * 16);
      async_ld16(Bb + row * NV + kt * 64 + (kb >> 1), ldsB + j * 4096 + wbase);
    }
    __syncthreads();
#pragma unroll
    for (int ks = 0; ks < 2; ++ks) {
      bf16x8 af[4], bfr[4];
#pragma unroll
      for (int mb = 0; mb < 4; ++mb) {
        int m = wm * 64 + mb * 16 + l16;
        int kb = (ks * 64 + quad * 16) ^ ((m & 7) * 16);
        af[mb] = *(const bf16x8*)(ldsA + m * 128 + kb);
      }
#pragma unroll
      for (int nb = 0; nb < 4; ++nb) {
        int nn = wn * 64 + nb * 16 + l16;
        int kb = (ks * 64 + quad * 16) ^ ((nn & 7) * 16);
        bfr[nb] = *(const bf16x8*)(ldsB + nn * 128 + kb);
      }
#pragma unroll
      for (int mb = 0; mb < 4; ++mb)
#pragma unroll
        for (int nb = 0; nb < 4; ++nb)
          acc[mb][nb] = __builtin_amdgcn_mfma_f32_16x16x32_bf16(af[mb], bfr[nb], acc[mb][nb], 0, 0, 0);
    }
  }
  // epilogue: D[n, v, col] = acc (raw; alpha/beta folded into consumers)
#pragma unroll
  for (int mb = 0; mb < 4; ++mb) {
#pragma unroll
    for (int r = 0; r < 4; ++r) {
      int v = mtile * 128 + wm * 64 + mb * 16 + quad * 4 + r;
#pragma unroll
      for (int nb = 0; nb < 4; ++nb) {
        int col = ntile * 128 + wn * 64 + nb * 16 + l16;
        dout[n * (NV * NC * NL) + v * (NC * NL) + col] = (__bf16)acc[mb][nb][r];
      }
    }
  }
}

// ---------------- conv (VALU + LDS bulk-DMA): out[n,o,v,l] = cb[o] + folded-w . {x,D1,D2} ----
// Per block (n,v): stage the whole input slab (x row-set 32 KB fp32, D1/D2 16 KB bf16
// contiguous) into LDS via global_load_lds (deep vmcnt queue, no VGPR round-trip),
// one barrier, then a pure-FMA phase reading LDS (consecutive lanes -> conflict-free).
// Fixes the R2/R6 latency gap: per-wave trickle loads -> 64 KB bulk transfer in flight.
// No launch_bounds (R5 lesson: VGPR caps spill acc[] to scratch).
__global__ void k_conv_valu(const float* __restrict__ x, const __bf16* __restrict__ d1,
                            const __bf16* __restrict__ d2, const float* __restrict__ cwT,
                            const float* __restrict__ cb, float* __restrict__ out) {
  __shared__ __align__(16) char clds[65536];
  float*  xs  = (float*)clds;              // [32][256] fp32, 32 KB
  __bf16* d1s = (__bf16*)(clds + 32768);   // [32][256] bf16, 16 KB (contiguous in global)
  __bf16* d2s = (__bf16*)(clds + 49152);   // 16 KB

  const int bid = blockIdx.x;              // NB*NV = 4096
  const int n = bid >> 9, v = bid & 511;
  const int tid = threadIdx.x;
  const int l = tid;
  const int wbase = (tid & ~63) * 16;      // wave-uniform LDS base for async_ld16

  // stage x rows: 32 rows of 1 KB (row c at stride NV*NL*4)
  const char* xg = (const char*)(x + (size_t)n * (NC * NV * NL) + (size_t)v * NL);
#pragma unroll
  for (int j = 0; j < 8; ++j) {
    int pos = j * 4096 + tid * 16;         // byte offset within xs
    int c   = pos >> 10;                   // 1 KB per row
    int off = pos & 1023;
    async_ld16(xg + (size_t)c * (NV * NL * 4) + off, clds + j * 4096 + wbase);
  }
  // stage D1/D2: 16 KB contiguous each
  const char* d1g = (const char*)(d1 + (size_t)(n * NV + v) * (NC * NL));
  const char* d2g = (const char*)(d2 + (size_t)(n * NV + v) * (NC * NL));
#pragma unroll
  for (int j = 0; j < 4; ++j)
    async_ld16(d1g + j * 4096 + tid * 16, clds + 32768 + j * 4096 + wbase);
#pragma unroll
  for (int j = 0; j < 4; ++j)
    async_ld16(d2g + j * 4096 + tid * 16, clds + 49152 + j * 4096 + wbase);
  __syncthreads();

  float acc[32];
#pragma unroll
  for (int o = 0; o < 32; ++o) acc[o] = 0.f;

#pragma unroll 2
  for (int c = 0; c < 32; ++c) {
    float xv = xs[c * 256 + l];
    float v1 = (float)d1s[c * 256 + l];
    float v2 = (float)d2s[c * 256 + l];
    const float* wx = cwT + c * 32;
    const float* w1 = cwT + (32 + c) * 32;
    const float* w2 = cwT + (64 + c) * 32;
#pragma unroll
    for (int o = 0; o < 32; ++o)
      acc[o] = fmaf(wx[o], xv, fmaf(w1[o], v1, fmaf(w2[o], v2, acc[o])));
  }

  float* op = out + (size_t)(n * NC * NV + v) * NL + l;   // out[((n*NC+o)*NV+v)*NL+l]
#pragma unroll
  for (int o = 0; o < 32; ++o) op[o * (NV * NL)] = acc[o] + cb[o];
}

// ---------------- launch ----------------
extern "C" void kernel_launch(void* const* d_in, const int* in_sizes, int n_in,
                              void* d_out, int out_size, void* d_ws, size_t ws_size,
                              hipStream_t stream) {
  const float* x   = (const float*)d_in[0];
  const float* adj = (const float*)d_in[1];
  const float* W   = (const float*)d_in[2];
  const float* b   = (const float*)d_in[3];
  const float* cw  = (const float*)d_in[4];
  const float* cb  = (const float*)d_in[5];
  float* out = (float*)d_out;
  char* ws = (char*)d_ws;

  // workspace layout (196.3 MiB total — byte-identical footprint to the verified round-0/2)
  float*  dinv    = (float*)ws;                               // 16 KiB
  float*  partial = (float*)(ws + 16384);                     // 128 KiB (dead after k_dinv)
  __bf16* Wt      = (__bf16*)(ws + 147456);                   // 128 KiB
  __bf16* abuf    = (__bf16*)(ws + 278528);                   // 4 MiB
  __bf16* slot1   = (__bf16*)(ws + 4472832);                  // 64 MiB: hwA, then D2
  __bf16* slot2   = (__bf16*)(ws + 4472832 + 67108864);       // 64 MiB: D1
  __bf16* slot3   = (__bf16*)(ws + 4472832 + 2 * 67108864);   // 64 MiB: hwB
  // cwT (12 KiB) reuses the partial region after k_dinv has consumed it
  float*  cwT     = partial;

  __bf16* hwA = slot1;
  __bf16* D1  = slot2;
  __bf16* hwB = slot3;
  __bf16* D2  = slot1;   // hwA dead after k_gemm_wt<false,1>

  k_colsum_part<<<128, 256, 0, stream>>>(adj, partial);
  k_dinv<<<16, 256, 0, stream>>>(partial, dinv);
  k_prep_cwt<<<12, 256, 0, stream>>>(cw, cwT);
  k_prep_a<<<8192, 256, 0, stream>>>(adj, dinv, abuf);
  k_prep_wt<<<256, 256, 0, stream>>>(W, Wt);

  // hwA = xW + b
  k_gemm_wt<true, 0><<<2048, 256, 0, stream>>>(Wt, (const void*)x, b, hwA, nullptr);
  // D1 = a @ hwA
  k_gemm_a<<<2048, 256, 0, stream>>>(abuf, hwA, D1);
  // hwB = alpha*hwA + beta*(D1*W + b)   (== h1 @ W + b)
  k_gemm_wt<false, 1><<<2048, 256, 0, stream>>>(Wt, (const void*)D1, b, hwB, hwA);
  // D2 = a @ hwB
  k_gemm_a<<<2048, 256, 0, stream>>>(abuf, hwB, D2);
  // out = cb + (Wx + a(W1+W2))x + bW1*D1 + bW2*D2
  k_conv_valu<<<4096, 256, 0, stream>>>(x, D1, D2, cwT, cb, out);
}

// Round 12
// 507.498 us; speedup vs baseline: 1.0220x; 1.0220x over previous
//
#include <hip/hip_runtime.h>

// Problem constants
constexpr int NB = 8;    // batch
constexpr int NC = 32;   // channels
constexpr int NV = 512;  // vertices
constexpr int NL = 256;  // features
constexpr float F_ALPHA = 0.05f;
constexpr float F_BETA  = 0.95f;   // == 1 - F_ALPHA (used for both roles)

typedef __bf16 bf16x8 __attribute__((ext_vector_type(8)));
typedef float  f32x4  __attribute__((ext_vector_type(4)));

// async global->LDS, 16B per lane; LDS dest = wave-uniform base + lane*16
__device__ __forceinline__ void async_ld16(const void* g, void* l) {
  __builtin_amdgcn_global_load_lds(
      (const __attribute__((address_space(1))) void*)g,
      (__attribute__((address_space(3))) void*)l, 16, 0, 0);
}

// ---------------- prep kernels ----------------

// partial column sums of adj: partial[n, chunk, w] = sum_{v in chunk*64..+64} adj[n,v,w]
__global__ void k_colsum_part(const float* __restrict__ adj, float* __restrict__ partial) {
  int idx = blockIdx.x * 256 + threadIdx.x;       // NB*8*NV = 32768
  int w = idx & 511;
  int chunk = (idx >> 9) & 7;
  int n = idx >> 12;
  const float* p = adj + n * (NV * NV) + chunk * 64 * NV + w;
  float s = 0.f;
#pragma unroll
  for (int v = 0; v < 64; ++v) s += p[v * NV];
  partial[idx] = s;
}

__global__ void k_dinv(const float* __restrict__ partial, float* __restrict__ dinv) {
  int idx = blockIdx.x * 256 + threadIdx.x;       // NB*NV = 4096
  int w = idx & 511;
  int n = idx >> 9;
  float s = 1.f;                                   // +1 from the identity on the diagonal
#pragma unroll
  for (int j = 0; j < 8; ++j) s += partial[n * 4096 + j * 512 + w];
  dinv[idx] = 1.f / s;
}

// a_bf16[n,v,w] = (adj[n,v,w] + (v==w)) * dinv[n,w]
__global__ void k_prep_a(const float* __restrict__ adj, const float* __restrict__ dinv,
                         __bf16* __restrict__ a) {
  int idx = blockIdx.x * 256 + threadIdx.x;       // NB*NV*NV
  int w = idx & 511;
  int v = (idx >> 9) & 511;
  int n = idx >> 18;
  float val = adj[idx] + (v == w ? 1.0f : 0.0f);
  a[idx] = (__bf16)(val * dinv[(n << 9) | w]);
}

// Wt[l,k] = W[k,l] in bf16
__global__ void k_prep_wt(const float* __restrict__ W, __bf16* __restrict__ Wt) {
  int idx = blockIdx.x * 256 + threadIdx.x;       // 65536
  int l = idx >> 8, k = idx & 255;
  Wt[idx] = (__bf16)W[(k << 8) | l];
}

// Folded conv weights, k-major: cwT[k][o], 96 x 32 fp32 (12 KiB).
//   k <  32 (x group):  Wx[o,k] + alpha*(W1[o,k] + W2[o,k])   [since h_g = alpha*x + beta*D_g]
//   32<=k<64 (D1 group): beta*W1[o,k-32]
//   64<=k<96 (D2 group): beta*W2[o,k-64]
__global__ void k_prep_cwt(const float* __restrict__ cw, float* __restrict__ cwT) {
  int idx = blockIdx.x * 256 + threadIdx.x;       // 3072
  if (idx < 3072) {
    int k = idx >> 5, o = idx & 31;
    float v;
    if (k < 32)      v = cw[o * 96 + k] + F_ALPHA * (cw[o * 96 + 32 + k] + cw[o * 96 + 64 + k]);
    else             v = F_BETA * cw[o * 96 + k];
    cwT[idx] = v;
  }
}

// ---------------- GEMM 1: hw^T = Wt @ B^T (+ epilogue) ----------------
// Per pair p=(n,c): acc[l][w] = sum_k Wt[l][k] * B[w][k], stored at hw[n,c,l,w].
// BF32: B-source is fp32 (x, layout [n,c,v,l]); else bf16 (D1, layout [n,v,c,l]).
// EPI 0: hw = acc + b[l]                       (first propagation: hw1 = xW + b)
// EPI 1: hw = alpha*hwprev + beta*(acc + b[l]) (second: hw2 = alpha*hw1 + beta*(D1*W + b),
//                                              exact since h1 = alpha*x + beta*D1, xW = hw1 - b)
template <bool BF32, int EPI>
__global__ __launch_bounds__(256, 2)
void k_gemm_wt(const __bf16* __restrict__ Wt, const void* __restrict__ Bsrc,
               const float* __restrict__ bias, __bf16* __restrict__ hw,
               const __bf16* __restrict__ hwprev) {
  __shared__ __align__(16) char lds[32768];
  char* ldsA = lds;
  char* ldsB = lds + 16384;

  const int tid = threadIdx.x;
  const int bid = blockIdx.x;
  const int p = bid >> 3;            // pair index n*NC+c
  const int mtile = (bid >> 2) & 1;  // M=256 -> 2 tiles of 128
  const int ntile = bid & 3;         // N=512 -> 4 tiles of 128
  const int n = p >> 5, c = p & 31;

  int Bbase, Bstride;
  if (BF32) { Bbase = p * (NV * NL); Bstride = NL; }               // x[n,c,w,k]
  else      { Bbase = n * (NV * NC * NL) + c * NL; Bstride = NC * NL; } // D1[n,w,c,k]

  const int wave = tid >> 6, lane = tid & 63;
  const int quad = lane >> 4, l16 = lane & 15;
  const int wm = wave >> 1, wn = wave & 1;
  const int wbase = (tid & ~63) * 16;

  f32x4 acc[4][4];
#pragma unroll
  for (int i = 0; i < 4; ++i)
#pragma unroll
    for (int j = 0; j < 4; ++j) acc[i][j] = (f32x4){0.f, 0.f, 0.f, 0.f};

  for (int kt = 0; kt < 256 / 64; ++kt) {
    __syncthreads();
    // stage A = Wt tile [128 x 64], swizzled
#pragma unroll
    for (int j = 0; j < 4; ++j) {
      int pos = j * 4096 + tid * 16;
      int row = pos >> 7;
      int kb = (pos & 127) ^ ((row & 7) * 16);
      const __bf16* g = Wt + (mtile * 128 + row) * 256 + kt * 64 + (kb >> 1);
      async_ld16(g, ldsA + j * 4096 + wbase);
    }
    // stage B tile [128 x 64]
    if (BF32) {
      const float* Bf = (const float*)Bsrc;
#pragma unroll
      for (int j = 0; j < 4; ++j) {
        int pos = j * 4096 + tid * 16;
        int row = pos >> 7;
        int kb = (pos & 127) ^ ((row & 7) * 16);
        const float* g = Bf + Bbase + (ntile * 128 + row) * Bstride + kt * 64 + (kb >> 1);
        float4 f0 = *(const float4*)g;
        float4 f1 = *(const float4*)(g + 4);
        bf16x8 vv;
        vv[0] = (__bf16)f0.x; vv[1] = (__bf16)f0.y; vv[2] = (__bf16)f0.z; vv[3] = (__bf16)f0.w;
        vv[4] = (__bf16)f1.x; vv[5] = (__bf16)f1.y; vv[6] = (__bf16)f1.z; vv[7] = (__bf16)f1.w;
        *(bf16x8*)(ldsB + pos) = vv;
      }
    } else {
      const __bf16* Bf = (const __bf16*)Bsrc;
#pragma unroll
      for (int j = 0; j < 4; ++j) {
        int pos = j * 4096 + tid * 16;
        int row = pos >> 7;
        int kb = (pos & 127) ^ ((row & 7) * 16);
        const __bf16* g = Bf + Bbase + (ntile * 128 + row) * Bstride + kt * 64 + (kb >> 1);
        async_ld16(g, ldsB + j * 4096 + wbase);
      }
    }
    __syncthreads();
#pragma unroll
    for (int ks = 0; ks < 2; ++ks) {
      bf16x8 af[4], bfr[4];
#pragma unroll
      for (int mb = 0; mb < 4; ++mb) {
        int m = wm * 64 + mb * 16 + l16;
        int kb = (ks * 64 + quad * 16) ^ ((m & 7) * 16);
        af[mb] = *(const bf16x8*)(ldsA + m * 128 + kb);
      }
#pragma unroll
      for (int nb = 0; nb < 4; ++nb) {
        int nn = wn * 64 + nb * 16 + l16;
        int kb = (ks * 64 + quad * 16) ^ ((nn & 7) * 16);
        bfr[nb] = *(const bf16x8*)(ldsB + nn * 128 + kb);
      }
#pragma unroll
      for (int mb = 0; mb < 4; ++mb)
#pragma unroll
        for (int nb = 0; nb < 4; ++nb)
          acc[mb][nb] = __builtin_amdgcn_mfma_f32_16x16x32_bf16(af[mb], bfr[nb], acc[mb][nb], 0, 0, 0);
    }
  }
  // epilogue: hw[n,c, l, w]
  const size_t obase = (size_t)p * (NL * NV) + mtile * 128 * NV + ntile * 128;
  __bf16* outp = hw + obase;
  const __bf16* prevp = (EPI == 1) ? hwprev + obase : nullptr;
#pragma unroll
  for (int mb = 0; mb < 4; ++mb) {
#pragma unroll
    for (int r = 0; r < 4; ++r) {
      int ml = wm * 64 + mb * 16 + quad * 4 + r;
      float bv = bias[mtile * 128 + ml];
#pragma unroll
      for (int nb = 0; nb < 4; ++nb) {
        int nl = wn * 64 + nb * 16 + l16;
        if (EPI == 0) {
          outp[ml * NV + nl] = (__bf16)(acc[mb][nb][r] + bv);
        } else {
          float pv = (float)prevp[ml * NV + nl];
          outp[ml * NV + nl] = (__bf16)(F_ALPHA * pv + F_BETA * (acc[mb][nb][r] + bv));
        }
      }
    }
  }
}

// ---------------- GEMM 2: D = a @ hw (raw diffusion term, no x epilogue) ----------------
// Per batch n: D[v, col=(c,l)] = sum_w a[n,v,w] * hw[n,c,l,w]; D[n,v,c,l] out (bf16).
__global__ __launch_bounds__(256, 2)
void k_gemm_a(const __bf16* __restrict__ abuf, const __bf16* __restrict__ hw,
              __bf16* __restrict__ dout) {
  __shared__ __align__(16) char lds[32768];
  char* ldsA = lds;
  char* ldsB = lds + 16384;

  const int tid = threadIdx.x;
  const int bid = blockIdx.x;
  const int n = bid >> 8;
  const int mtile = (bid >> 6) & 3;  // M=512 -> 4
  const int ntile = bid & 63;        // N=8192 -> 64

  const __bf16* Ab = abuf + n * (NV * NV) + mtile * 128 * NV;        // rows v, stride 512
  const __bf16* Bb = hw + n * (NC * NL * NV) + ntile * 128 * NV;     // rows col, stride 512

  const int wave = tid >> 6, lane = tid & 63;
  const int quad = lane >> 4, l16 = lane & 15;
  const int wm = wave >> 1, wn = wave & 1;
  const int wbase = (tid & ~63) * 16;

  f32x4 acc[4][4];
#pragma unroll
  for (int i = 0; i < 4; ++i)
#pragma unroll
    for (int j = 0; j < 4; ++j) acc[i][j] = (f32x4){0.f, 0.f, 0.f, 0.f};

  for (int kt = 0; kt < 512 / 64; ++kt) {
    __syncthreads();
#pragma unroll
    for (int j = 0; j < 4; ++j) {
      int pos = j * 4096 + tid * 16;
      int row = pos >> 7;
      int kb = (pos & 127) ^ ((row & 7) * 16);
      async_ld16(Ab + row * NV + kt * 64 + (kb >> 1), ldsA + j * 4096 + wbase);
    }
#pragma unroll
    for (int j = 0; j < 4; ++j) {
      int pos = j * 4096 + tid * 16;
      int row = pos >> 7;
      int kb = (pos & 127) ^ ((row & 7) * 16);
      async_ld16(Bb + row * NV + kt * 64 + (kb >> 1), ldsB + j * 4096 + wbase);
    }
    __syncthreads();
#pragma unroll
    for (int ks = 0; ks < 2; ++ks) {
      bf16x8 af[4], bfr[4];
#pragma unroll
      for (int mb = 0; mb < 4; ++mb) {
        int m = wm * 64 + mb * 16 + l16;
        int kb = (ks * 64 + quad * 16) ^ ((m & 7) * 16);
        af[mb] = *(const bf16x8*)(ldsA + m * 128 + kb);
      }
#pragma unroll
      for (int nb = 0; nb < 4; ++nb) {
        int nn = wn * 64 + nb * 16 + l16;
        int kb = (ks * 64 + quad * 16) ^ ((nn & 7) * 16);
        bfr[nb] = *(const bf16x8*)(ldsB + nn * 128 + kb);
      }
#pragma unroll
      for (int mb = 0; mb < 4; ++mb)
#pragma unroll
        for (int nb = 0; nb < 4; ++nb)
          acc[mb][nb] = __builtin_amdgcn_mfma_f32_16x16x32_bf16(af[mb], bfr[nb], acc[mb][nb], 0, 0, 0);
    }
  }
  // epilogue: D[n, v, col] = acc (raw; alpha/beta folded into consumers)
#pragma unroll
  for (int mb = 0; mb < 4; ++mb) {
#pragma unroll
    for (int r = 0; r < 4; ++r) {
      int v = mtile * 128 + wm * 64 + mb * 16 + quad * 4 + r;
#pragma unroll
      for (int nb = 0; nb < 4; ++nb) {
        int col = ntile * 128 + wn * 64 + nb * 16 + l16;
        dout[n * (NV * NC * NL) + v * (NC * NL) + col] = (__bf16)acc[mb][nb][r];
      }
    }
  }
}

// ---------------- conv (VALU, full register prefetch): out = cb + folded-w . {x,D1,D2} ----
// One thread per (n,v,l). ALL 96 per-thread loads (32 x fp32 HBM + 2x32 D bf16 L3) are
// address-independent of the compute, so they are issued in an unrolled prologue into
// register arrays (static indices -> VGPRs). The compiler inserts counted vmcnt waits:
// one ~900-cycle wait on the first x element, near-zero after (loads pipeline through
// HBM under the 96-FMA bursts). No LDS (R10 lesson: 64KB LDS -> 2 blocks/CU -> no
// overlap), no launch_bounds (R5 lesson: VGPR cap spills acc to scratch).
__global__ void k_conv_valu(const float* __restrict__ x, const __bf16* __restrict__ d1,
                            const __bf16* __restrict__ d2, const float* __restrict__ cwT,
                            const float* __restrict__ cb, float* __restrict__ out) {
  const int bid = blockIdx.x;              // NB*NV = 4096
  const int n = bid >> 9, v = bid & 511;
  const int l = threadIdx.x;

  const float*  xp = x  + (size_t)n * (NC * NV * NL) + (size_t)v * NL + l;  // + c*NV*NL
  const __bf16* p1 = d1 + (size_t)(n * NV + v) * (NC * NL) + l;             // + c*NL
  const __bf16* p2 = d2 + (size_t)(n * NV + v) * (NC * NL) + l;

  // full prefetch: issue x (HBM, longest latency) first, then D1/D2 (L3-hot)
  float xv[32];
#pragma unroll
  for (int c = 0; c < 32; ++c) xv[c] = xp[c * (NV * NL)];
  __bf16 e1[32], e2[32];
#pragma unroll
  for (int c = 0; c < 32; ++c) e1[c] = p1[c * NL];
#pragma unroll
  for (int c = 0; c < 32; ++c) e2[c] = p2[c * NL];

  float acc[32];
#pragma unroll
  for (int o = 0; o < 32; ++o) acc[o] = 0.f;

#pragma unroll
  for (int c = 0; c < 32; ++c) {
    const float a0 = xv[c];
    const float v1 = (float)e1[c];
    const float v2 = (float)e2[c];
    const float* wx = cwT + c * 32;
    const float* w1 = cwT + (32 + c) * 32;
    const float* w2 = cwT + (64 + c) * 32;
#pragma unroll
    for (int o = 0; o < 32; ++o)
      acc[o] = fmaf(wx[o], a0, fmaf(w1[o], v1, fmaf(w2[o], v2, acc[o])));
  }

  float* op = out + (size_t)(n * NC * NV + v) * NL + l;   // out[((n*NC+o)*NV+v)*NL+l]
#pragma unroll
  for (int o = 0; o < 32; ++o) op[o * (NV * NL)] = acc[o] + cb[o];
}

// ---------------- launch ----------------
extern "C" void kernel_launch(void* const* d_in, const int* in_sizes, int n_in,
                              void* d_out, int out_size, void* d_ws, size_t ws_size,
                              hipStream_t stream) {
  const float* x   = (const float*)d_in[0];
  const float* adj = (const float*)d_in[1];
  const float* W   = (const float*)d_in[2];
  const float* b   = (const float*)d_in[3];
  const float* cw  = (const float*)d_in[4];
  const float* cb  = (const float*)d_in[5];
  float* out = (float*)d_out;
  char* ws = (char*)d_ws;

  // workspace layout (196.3 MiB total — byte-identical footprint to the verified round-0/2)
  float*  dinv    = (float*)ws;                               // 16 KiB
  float*  partial = (float*)(ws + 16384);                     // 128 KiB (dead after k_dinv)
  __bf16* Wt      = (__bf16*)(ws + 147456);                   // 128 KiB
  __bf16* abuf    = (__bf16*)(ws + 278528);                   // 4 MiB
  __bf16* slot1   = (__bf16*)(ws + 4472832);                  // 64 MiB: hwA, then D2
  __bf16* slot2   = (__bf16*)(ws + 4472832 + 67108864);       // 64 MiB: D1
  __bf16* slot3   = (__bf16*)(ws + 4472832 + 2 * 67108864);   // 64 MiB: hwB
  // cwT (12 KiB) reuses the partial region after k_dinv has consumed it
  float*  cwT     = partial;

  __bf16* hwA = slot1;
  __bf16* D1  = slot2;
  __bf16* hwB = slot3;
  __bf16* D2  = slot1;   // hwA dead after k_gemm_wt<false,1>

  k_colsum_part<<<128, 256, 0, stream>>>(adj, partial);
  k_dinv<<<16, 256, 0, stream>>>(partial, dinv);
  k_prep_cwt<<<12, 256, 0, stream>>>(cw, cwT);
  k_prep_a<<<8192, 256, 0, stream>>>(adj, dinv, abuf);
  k_prep_wt<<<256, 256, 0, stream>>>(W, Wt);

  // hwA = xW + b
  k_gemm_wt<true, 0><<<2048, 256, 0, stream>>>(Wt, (const void*)x, b, hwA, nullptr);
  // D1 = a @ hwA
  k_gemm_a<<<2048, 256, 0, stream>>>(abuf, hwA, D1);
  // hwB = alpha*hwA + beta*(D1*W + b)   (== h1 @ W + b)
  k_gemm_wt<false, 1><<<2048, 256, 0, stream>>>(Wt, (const void*)D1, b, hwB, hwA);
  // D2 = a @ hwB
  k_gemm_a<<<2048, 256, 0, stream>>>(abuf, hwB, D2);
  // out = cb + (Wx + a(W1+W2))x + bW1*D1 + bW2*D2
  k_conv_valu<<<4096, 256, 0, stream>>>(x, D1, D2, cwT, cb, out);
}

// Round 13
// 457.068 us; speedup vs baseline: 1.1348x; 1.1103x over previous
//
#include <hip/hip_runtime.h>

// Problem constants
constexpr int NB = 8;    // batch
constexpr int NC = 32;   // channels
constexpr int NV = 512;  // vertices
constexpr int NL = 256;  // features
constexpr float F_ALPHA = 0.05f;
constexpr float F_BETA  = 0.95f;   // == 1 - F_ALPHA (used for both roles)

typedef __bf16 bf16x8 __attribute__((ext_vector_type(8)));
typedef float  f32x4  __attribute__((ext_vector_type(4)));

// async global->LDS, 16B per lane; LDS dest = wave-uniform base + lane*16
__device__ __forceinline__ void async_ld16(const void* g, void* l) {
  __builtin_amdgcn_global_load_lds(
      (const __attribute__((address_space(1))) void*)g,
      (__attribute__((address_space(3))) void*)l, 16, 0, 0);
}

// ---------------- prep kernels ----------------

// partial column sums of adj: partial[n, chunk, w] = sum_{v in chunk*64..+64} adj[n,v,w]
__global__ void k_colsum_part(const float* __restrict__ adj, float* __restrict__ partial) {
  int idx = blockIdx.x * 256 + threadIdx.x;       // NB*8*NV = 32768
  int w = idx & 511;
  int chunk = (idx >> 9) & 7;
  int n = idx >> 12;
  const float* p = adj + n * (NV * NV) + chunk * 64 * NV + w;
  float s = 0.f;
#pragma unroll
  for (int v = 0; v < 64; ++v) s += p[v * NV];
  partial[idx] = s;
}

__global__ void k_dinv(const float* __restrict__ partial, float* __restrict__ dinv) {
  int idx = blockIdx.x * 256 + threadIdx.x;       // NB*NV = 4096
  int w = idx & 511;
  int n = idx >> 9;
  float s = 1.f;                                   // +1 from the identity on the diagonal
#pragma unroll
  for (int j = 0; j < 8; ++j) s += partial[n * 4096 + j * 512 + w];
  dinv[idx] = 1.f / s;
}

// a_bf16[n,v,w] = (adj[n,v,w] + (v==w)) * dinv[n,w]
__global__ void k_prep_a(const float* __restrict__ adj, const float* __restrict__ dinv,
                         __bf16* __restrict__ a) {
  int idx = blockIdx.x * 256 + threadIdx.x;       // NB*NV*NV
  int w = idx & 511;
  int v = (idx >> 9) & 511;
  int n = idx >> 18;
  float val = adj[idx] + (v == w ? 1.0f : 0.0f);
  a[idx] = (__bf16)(val * dinv[(n << 9) | w]);
}

// Wt[l,k] = W[k,l] in bf16
__global__ void k_prep_wt(const float* __restrict__ W, __bf16* __restrict__ Wt) {
  int idx = blockIdx.x * 256 + threadIdx.x;       // 65536
  int l = idx >> 8, k = idx & 255;
  Wt[idx] = (__bf16)W[(k << 8) | l];
}

// Folded conv weights, o-major: cwF[o][k], 32 x 96 fp32 (12 KiB).
//   k <  32 (x group):  Wx[o,k] + alpha*(W1[o,k] + W2[o,k])   [since h_g = alpha*x + beta*D_g]
//   32<=k<64 (D1 group): beta*W1[o,k-32]
//   64<=k<96 (D2 group): beta*W2[o,k-64]
__global__ void k_prep_cwf(const float* __restrict__ cw, float* __restrict__ cwF) {
  int idx = blockIdx.x * 256 + threadIdx.x;       // 3072
  if (idx < 3072) {
    int o = idx / 96, k = idx - o * 96;
    float v;
    if (k < 32)      v = cw[o * 96 + k] + F_ALPHA * (cw[o * 96 + 32 + k] + cw[o * 96 + 64 + k]);
    else             v = F_BETA * cw[o * 96 + k];
    cwF[idx] = v;
  }
}

// ---------------- GEMM 1: hw^T = Wt @ B^T (+ epilogue) ----------------
// Per pair p=(n,c): acc[l][w] = sum_k Wt[l][k] * B[w][k], stored at hw[n,c,l,w].
// BF32: B-source is fp32 (x, layout [n,c,v,l]); else bf16 (D1, layout [n,v,c,l]).
// EPI 0: hw = acc + b[l]                       (first propagation: hw1 = xW + b)
// EPI 1: hw = alpha*hwprev + beta*(acc + b[l]) (second: hw2 = alpha*hw1 + beta*(D1*W + b),
//                                              exact since h1 = alpha*x + beta*D1, xW = hw1 - b)
template <bool BF32, int EPI>
__global__ __launch_bounds__(256, 2)
void k_gemm_wt(const __bf16* __restrict__ Wt, const void* __restrict__ Bsrc,
               const float* __restrict__ bias, __bf16* __restrict__ hw,
               const __bf16* __restrict__ hwprev) {
  __shared__ __align__(16) char lds[32768];
  char* ldsA = lds;
  char* ldsB = lds + 16384;

  const int tid = threadIdx.x;
  const int bid = blockIdx.x;
  const int p = bid >> 3;            // pair index n*NC+c
  const int mtile = (bid >> 2) & 1;  // M=256 -> 2 tiles of 128
  const int ntile = bid & 3;         // N=512 -> 4 tiles of 128
  const int n = p >> 5, c = p & 31;

  int Bbase, Bstride;
  if (BF32) { Bbase = p * (NV * NL); Bstride = NL; }               // x[n,c,w,k]
  else      { Bbase = n * (NV * NC * NL) + c * NL; Bstride = NC * NL; } // D1[n,w,c,k]

  const int wave = tid >> 6, lane = tid & 63;
  const int quad = lane >> 4, l16 = lane & 15;
  const int wm = wave >> 1, wn = wave & 1;
  const int wbase = (tid & ~63) * 16;

  f32x4 acc[4][4];
#pragma unroll
  for (int i = 0; i < 4; ++i)
#pragma unroll
    for (int j = 0; j < 4; ++j) acc[i][j] = (f32x4){0.f, 0.f, 0.f, 0.f};

  for (int kt = 0; kt < 256 / 64; ++kt) {
    __syncthreads();
    // stage A = Wt tile [128 x 64], swizzled
#pragma unroll
    for (int j = 0; j < 4; ++j) {
      int pos = j * 4096 + tid * 16;
      int row = pos >> 7;
      int kb = (pos & 127) ^ ((row & 7) * 16);
      const __bf16* g = Wt + (mtile * 128 + row) * 256 + kt * 64 + (kb >> 1);
      async_ld16(g, ldsA + j * 4096 + wbase);
    }
    // stage B tile [128 x 64]
    if (BF32) {
      const float* Bf = (const float*)Bsrc;
#pragma unroll
      for (int j = 0; j < 4; ++j) {
        int pos = j * 4096 + tid * 16;
        int row = pos >> 7;
        int kb = (pos & 127) ^ ((row & 7) * 16);
        const float* g = Bf + Bbase + (ntile * 128 + row) * Bstride + kt * 64 + (kb >> 1);
        float4 f0 = *(const float4*)g;
        float4 f1 = *(const float4*)(g + 4);
        bf16x8 vv;
        vv[0] = (__bf16)f0.x; vv[1] = (__bf16)f0.y; vv[2] = (__bf16)f0.z; vv[3] = (__bf16)f0.w;
        vv[4] = (__bf16)f1.x; vv[5] = (__bf16)f1.y; vv[6] = (__bf16)f1.z; vv[7] = (__bf16)f1.w;
        *(bf16x8*)(ldsB + pos) = vv;
      }
    } else {
      const __bf16* Bf = (const __bf16*)Bsrc;
#pragma unroll
      for (int j = 0; j < 4; ++j) {
        int pos = j * 4096 + tid * 16;
        int row = pos >> 7;
        int kb = (pos & 127) ^ ((row & 7) * 16);
        const __bf16* g = Bf + Bbase + (ntile * 128 + row) * Bstride + kt * 64 + (kb >> 1);
        async_ld16(g, ldsB + j * 4096 + wbase);
      }
    }
    __syncthreads();
#pragma unroll
    for (int ks = 0; ks < 2; ++ks) {
      bf16x8 af[4], bfr[4];
#pragma unroll
      for (int mb = 0; mb < 4; ++mb) {
        int m = wm * 64 + mb * 16 + l16;
        int kb = (ks * 64 + quad * 16) ^ ((m & 7) * 16);
        af[mb] = *(const bf16x8*)(ldsA + m * 128 + kb);
      }
#pragma unroll
      for (int nb = 0; nb < 4; ++nb) {
        int nn = wn * 64 + nb * 16 + l16;
        int kb = (ks * 64 + quad * 16) ^ ((nn & 7) * 16);
        bfr[nb] = *(const bf16x8*)(ldsB + nn * 128 + kb);
      }
#pragma unroll
      for (int mb = 0; mb < 4; ++mb)
#pragma unroll
        for (int nb = 0; nb < 4; ++nb)
          acc[mb][nb] = __builtin_amdgcn_mfma_f32_16x16x32_bf16(af[mb], bfr[nb], acc[mb][nb], 0, 0, 0);
    }
  }
  // epilogue: hw[n,c, l, w]
  const size_t obase = (size_t)p * (NL * NV) + mtile * 128 * NV + ntile * 128;
  __bf16* outp = hw + obase;
  const __bf16* prevp = (EPI == 1) ? hwprev + obase : nullptr;
#pragma unroll
  for (int mb = 0; mb < 4; ++mb) {
#pragma unroll
    for (int r = 0; r < 4; ++r) {
      int ml = wm * 64 + mb * 16 + quad * 4 + r;
      float bv = bias[mtile * 128 + ml];
#pragma unroll
      for (int nb = 0; nb < 4; ++nb) {
        int nl = wn * 64 + nb * 16 + l16;
        if (EPI == 0) {
          outp[ml * NV + nl] = (__bf16)(acc[mb][nb][r] + bv);
        } else {
          float pv = (float)prevp[ml * NV + nl];
          outp[ml * NV + nl] = (__bf16)(F_ALPHA * pv + F_BETA * (acc[mb][nb][r] + bv));
        }
      }
    }
  }
}

// ---------------- GEMM 2: D = a @ hw (raw diffusion term, no x epilogue) ----------------
// Per batch n: D[v, col=(c,l)] = sum_w a[n,v,w] * hw[n,c,l,w]; D[n,v,c,l] out (bf16).
__global__ __launch_bounds__(256, 2)
void k_gemm_a(const __bf16* __restrict__ abuf, const __bf16* __restrict__ hw,
              __bf16* __restrict__ dout) {
  __shared__ __align__(16) char lds[32768];
  char* ldsA = lds;
  char* ldsB = lds + 16384;

  const int tid = threadIdx.x;
  const int bid = blockIdx.x;
  const int n = bid >> 8;
  const int mtile = (bid >> 6) & 3;  // M=512 -> 4
  const int ntile = bid & 63;        // N=8192 -> 64

  const __bf16* Ab = abuf + n * (NV * NV) + mtile * 128 * NV;        // rows v, stride 512
  const __bf16* Bb = hw + n * (NC * NL * NV) + ntile * 128 * NV;     // rows col, stride 512

  const int wave = tid >> 6, lane = tid & 63;
  const int quad = lane >> 4, l16 = lane & 15;
  const int wm = wave >> 1, wn = wave & 1;
  const int wbase = (tid & ~63) * 16;

  f32x4 acc[4][4];
#pragma unroll
  for (int i = 0; i < 4; ++i)
#pragma unroll
    for (int j = 0; j < 4; ++j) acc[i][j] = (f32x4){0.f, 0.f, 0.f, 0.f};

  for (int kt = 0; kt < 512 / 64; ++kt) {
    __syncthreads();
#pragma unroll
    for (int j = 0; j < 4; ++j) {
      int pos = j * 4096 + tid * 16;
      int row = pos >> 7;
      int kb = (pos & 127) ^ ((row & 7) * 16);
      async_ld16(Ab + row * NV + kt * 64 + (kb >> 1), ldsA + j * 4096 + wbase);
    }
#pragma unroll
    for (int j = 0; j < 4; ++j) {
      int pos = j * 4096 + tid * 16;
      int row = pos >> 7;
      int kb = (pos & 127) ^ ((row & 7) * 16);
      async_ld16(Bb + row * NV + kt * 64 + (kb >> 1), ldsB + j * 4096 + wbase);
    }
    __syncthreads();
#pragma unroll
    for (int ks = 0; ks < 2; ++ks) {
      bf16x8 af[4], bfr[4];
#pragma unroll
      for (int mb = 0; mb < 4; ++mb) {
        int m = wm * 64 + mb * 16 + l16;
        int kb = (ks * 64 + quad * 16) ^ ((m & 7) * 16);
        af[mb] = *(const bf16x8*)(ldsA + m * 128 + kb);
      }
#pragma unroll
      for (int nb = 0; nb < 4; ++nb) {
        int nn = wn * 64 + nb * 16 + l16;
        int kb = (ks * 64 + quad * 16) ^ ((nn & 7) * 16);
        bfr[nb] = *(const bf16x8*)(ldsB + nn * 128 + kb);
      }
#pragma unroll
      for (int mb = 0; mb < 4; ++mb)
#pragma unroll
        for (int nb = 0; nb < 4; ++nb)
          acc[mb][nb] = __builtin_amdgcn_mfma_f32_16x16x32_bf16(af[mb], bfr[nb], acc[mb][nb], 0, 0, 0);
    }
  }
  // epilogue: D[n, v, col] = acc (raw; alpha/beta folded into consumers)
#pragma unroll
  for (int mb = 0; mb < 4; ++mb) {
#pragma unroll
    for (int r = 0; r < 4; ++r) {
      int v = mtile * 128 + wm * 64 + mb * 16 + quad * 4 + r;
#pragma unroll
      for (int nb = 0; nb < 4; ++nb) {
        int col = ntile * 128 + wn * 64 + nb * 16 + l16;
        dout[n * (NV * NC * NL) + v * (NC * NL) + col] = (__bf16)acc[mb][nb][r];
      }
    }
  }
}

// ---------------- conv (MFMA, round-0 measured-93us body): out[n,o,v,l] ----------------
// Revert of rounds 1-12's VALU experiments (all measured 105-151us; this measured 93us).
// Per block (n,v): tiny GEMM out[32 o x 256 l] = cwF[32 x 96] @ Bt[96 x 256] via
// 16x16x32 MFMA. Bt staged transposed [l][k] (thread tid owns row l=tid, pk-packed
// 16B stores); Aw staged from folded o-major weights. Inputs are x + D1/D2 (same
// [n,v,c,l] addressing round-0 used for h1/h2; weight folding identity verified R4-R12).
__global__ __launch_bounds__(256, 2)
void k_conv(const float* __restrict__ x, const __bf16* __restrict__ d1,
            const __bf16* __restrict__ d2, const float* __restrict__ cwF,
            const float* __restrict__ cb, float* __restrict__ out) {
  // Bt: 256 rows (l) x 104 bf16 (k, padded from 96), row stride 208B; Aw: 32 rows (o) x 104
  __shared__ __align__(16) char lds[288 * 208];
  char* Bt = lds;
  char* Aw = lds + 256 * 208;

  const int tid = threadIdx.x;
  const int bid = blockIdx.x;
  const int n = bid >> 9, v = bid & 511;

  // stage folded weights (32x96 fp32 -> bf16)
  for (int i = tid; i < 3072; i += 256) {
    int o = i / 96, k = i - o * 96;
    *(__bf16*)(Aw + o * 208 + k * 2) = (__bf16)cwF[i];
  }

  // stage transposed channel slab: Bt[l][k], thread tid owns row l=tid
  {
    const int l = tid;
    bf16x8 pk;
    const float* xp = x + n * (NC * NV * NL) + v * NL + l;
#pragma unroll
    for (int c = 0; c < 32; ++c) {
      pk[c & 7] = (__bf16)xp[c * (NV * NL)];
      if ((c & 7) == 7) *(bf16x8*)(Bt + l * 208 + (c - 7) * 2) = pk;
    }
    const __bf16* hp1 = d1 + (n * NV + v) * (NC * NL) + l;
#pragma unroll
    for (int c = 0; c < 32; ++c) {
      pk[c & 7] = hp1[c * NL];
      if ((c & 7) == 7) *(bf16x8*)(Bt + l * 208 + (32 + c - 7) * 2) = pk;
    }
    const __bf16* hp2 = d2 + (n * NV + v) * (NC * NL) + l;
#pragma unroll
    for (int c = 0; c < 32; ++c) {
      pk[c & 7] = hp2[c * NL];
      if ((c & 7) == 7) *(bf16x8*)(Bt + l * 208 + (64 + c - 7) * 2) = pk;
    }
  }
  __syncthreads();

  const int wave = tid >> 6, lane = tid & 63;
  const int quad = lane >> 4, l16 = lane & 15;

  f32x4 acc[2][4];
#pragma unroll
  for (int i = 0; i < 2; ++i)
#pragma unroll
    for (int j = 0; j < 4; ++j) acc[i][j] = (f32x4){0.f, 0.f, 0.f, 0.f};

#pragma unroll
  for (int ks = 0; ks < 3; ++ks) {
    bf16x8 af[2], bfr[4];
#pragma unroll
    for (int mt = 0; mt < 2; ++mt) {
      int m = mt * 16 + l16;
      af[mt] = *(const bf16x8*)(Aw + m * 208 + ks * 64 + quad * 16);
    }
#pragma unroll
    for (int nb = 0; nb < 4; ++nb) {
      int ll = wave * 64 + nb * 16 + l16;
      bfr[nb] = *(const bf16x8*)(Bt + ll * 208 + ks * 64 + quad * 16);
    }
#pragma unroll
    for (int mt = 0; mt < 2; ++mt)
#pragma unroll
      for (int nb = 0; nb < 4; ++nb)
        acc[mt][nb] = __builtin_amdgcn_mfma_f32_16x16x32_bf16(af[mt], bfr[nb], acc[mt][nb], 0, 0, 0);
  }

#pragma unroll
  for (int mt = 0; mt < 2; ++mt) {
#pragma unroll
    for (int r = 0; r < 4; ++r) {
      int o = mt * 16 + quad * 4 + r;
      float bo = cb[o];
#pragma unroll
      for (int nb = 0; nb < 4; ++nb) {
        int ll = wave * 64 + nb * 16 + l16;
        out[((n * NC + o) * NV + v) * NL + ll] = acc[mt][nb][r] + bo;
      }
    }
  }
}

// ---------------- launch ----------------
extern "C" void kernel_launch(void* const* d_in, const int* in_sizes, int n_in,
                              void* d_out, int out_size, void* d_ws, size_t ws_size,
                              hipStream_t stream) {
  const float* x   = (const float*)d_in[0];
  const float* adj = (const float*)d_in[1];
  const float* W   = (const float*)d_in[2];
  const float* b   = (const float*)d_in[3];
  const float* cw  = (const float*)d_in[4];
  const float* cb  = (const float*)d_in[5];
  float* out = (float*)d_out;
  char* ws = (char*)d_ws;

  // workspace layout (196.3 MiB total — byte-identical footprint to the verified round-0/2)
  float*  dinv    = (float*)ws;                               // 16 KiB
  float*  partial = (float*)(ws + 16384);                     // 128 KiB (dead after k_dinv)
  __bf16* Wt      = (__bf16*)(ws + 147456);                   // 128 KiB
  __bf16* abuf    = (__bf16*)(ws + 278528);                   // 4 MiB
  __bf16* slot1   = (__bf16*)(ws + 4472832);                  // 64 MiB: hwA, then D2
  __bf16* slot2   = (__bf16*)(ws + 4472832 + 67108864);       // 64 MiB: D1
  __bf16* slot3   = (__bf16*)(ws + 4472832 + 2 * 67108864);   // 64 MiB: hwB
  // cwF (12 KiB) reuses the partial region after k_dinv has consumed it
  float*  cwF     = partial;

  __bf16* hwA = slot1;
  __bf16* D1  = slot2;
  __bf16* hwB = slot3;
  __bf16* D2  = slot1;   // hwA dead after k_gemm_wt<false,1>

  k_colsum_part<<<128, 256, 0, stream>>>(adj, partial);
  k_dinv<<<16, 256, 0, stream>>>(partial, dinv);
  k_prep_cwf<<<12, 256, 0, stream>>>(cw, cwF);
  k_prep_a<<<8192, 256, 0, stream>>>(adj, dinv, abuf);
  k_prep_wt<<<256, 256, 0, stream>>>(W, Wt);

  // hwA = xW + b
  k_gemm_wt<true, 0><<<2048, 256, 0, stream>>>(Wt, (const void*)x, b, hwA, nullptr);
  // D1 = a @ hwA
  k_gemm_a<<<2048, 256, 0, stream>>>(abuf, hwA, D1);
  // hwB = alpha*hwA + beta*(D1*W + b)   (== h1 @ W + b)
  k_gemm_wt<false, 1><<<2048, 256, 0, stream>>>(Wt, (const void*)D1, b, hwB, hwA);
  // D2 = a @ hwB
  k_gemm_a<<<2048, 256, 0, stream>>>(abuf, hwB, D2);
  // out = cb + (Wx + a(W1+W2))x + bW1*D1 + bW2*D2
  k_conv<<<4096, 256, 0, stream>>>(x, D1, D2, cwF, cb, out);
}